// Round 3
// baseline (2413.474 us; speedup 1.0000x reference)
//
#include <hip/hip_runtime.h>
#include <math.h>

// Problem: B=64, T=512, D=64, K=12, P=100
// loss = -sum(gamma * logp)/ (B*T) + (s/P)*(0.05*||mu_diff||^2_masked + 0.05*||L_diff||^2_masked)
// logp[b,k,t] = -0.5*||L^-1 (x - mu)||^2 - sum(log diag L) - 0.5*D*log(2pi)

#define DD 64
#define BS 256

__device__ __forceinline__ float waveReduceSum(float v) {
#pragma unroll
  for (int off = 32; off > 0; off >>= 1) v += __shfl_down(v, off, 64);
  return v;
}

// ws layout (bytes):
// [0]   double nll_acc
// [8]   double mu_acc
// [16]  double L_acc
// [32]  float mask[128]

__global__ void init_kernel(const int* __restrict__ sid, float* __restrict__ maskf,
                            double* __restrict__ accs, int B, int P) {
  int tid = threadIdx.x;
  if (tid < 3) accs[tid] = 0.0;
  if (tid < P) maskf[tid] = 0.0f;
  __syncthreads();
  if (tid < B) maskf[sid[tid]] = 1.0f;  // benign write race, same value
}

__global__ __launch_bounds__(BS) void nll_kernel(
    const float* __restrict__ x, const float* __restrict__ mu_subj,
    const float* __restrict__ L_subj, const float* __restrict__ gamma,
    const int* __restrict__ sid, double* __restrict__ nll_acc,
    int T, int K) {
  __shared__ float Ls[DD][DD];      // 16 KB; reads are wave-uniform broadcasts
  __shared__ float mu_s[DD];
  __shared__ float rinv_s[DD];
  __shared__ float red[4];
  __shared__ float logdet_s;

  const int bx = blockIdx.x;
  const int b = bx / K, k = bx % K;
  const int tid = threadIdx.x;
  const int s = sid[b];
  const float* Lg  = L_subj  + ((size_t)s * K + k) * (DD * DD);
  const float* mug = mu_subj + ((size_t)s * K + k) * DD;

  // stage L (4096 floats) + mu (64 floats) into LDS, coalesced float4
#pragma unroll
  for (int q = 0; q < 4; ++q) {
    int off = q * (BS * 4) + tid * 4;
    *(float4*)((float*)Ls + off) = *(const float4*)(Lg + off);
  }
  if (tid < DD / 4) ((float4*)mu_s)[tid] = ((const float4*)mug)[tid];
  __syncthreads();

  if (tid < DD) {  // exactly wave 0
    float d = Ls[tid][tid];
    rinv_s[tid] = 1.0f / d;
    float lg = logf(d);
    lg = waveReduceSum(lg);
    if (tid == 0) logdet_s = lg;
  }
  __syncthreads();

  const float C0 = 58.81206612509905f;  // 0.5 * 64 * log(2*pi)
  const float logdet = logdet_s;
  float acc = 0.f;

  for (int t0 = tid; t0 < T; t0 += 2 * BS) {
    const int t1 = t0 + BS;
    const bool has1 = (t1 < T);
    float y0[DD], y1[DD];
    const float4* xr0 = (const float4*)(x + ((size_t)b * T + t0) * DD);
    const float4* xr1 = (const float4*)(x + ((size_t)b * T + (has1 ? t1 : t0)) * DD);

    // issue gamma loads EARLY so their HBM/L2 latency hides under the FMA chain
    const size_t gbase = (size_t)b * T;
    float g0 = gamma[(gbase + t0) * K + k];
    float g1 = has1 ? gamma[(gbase + t1) * K + k] : 0.f;

#pragma unroll
    for (int q = 0; q < DD / 4; ++q) {
      float4 a = xr0[q], c = xr1[q];
      float4 m = ((const float4*)mu_s)[q];
      y0[4*q+0] = a.x - m.x; y0[4*q+1] = a.y - m.y;
      y0[4*q+2] = a.z - m.z; y0[4*q+3] = a.w - m.w;
      y1[4*q+0] = c.x - m.x; y1[4*q+1] = c.y - m.y;
      y1[4*q+2] = c.z - m.z; y1[4*q+3] = c.w - m.w;
    }
    float maha0 = 0.f, maha1 = 0.f;
    // forward substitution: y_i = (r_i - sum_{j<i} L_ij y_j) / L_ii
    // fully unrolled (y0/y1 MUST stay in registers — no runtime indexing)
    // a0/a1 are independent 4-cyc FMA chains -> one wave saturates VALU issue
#pragma unroll
    for (int i = 0; i < DD; ++i) {
      float a0 = y0[i], a1 = y1[i];
#pragma unroll
      for (int j = 0; j + 3 < i; j += 4) {
        float4 Lq = *(const float4*)&Ls[i][j];   // ds_read_b128, broadcast
        a0 -= Lq.x * y0[j+0]; a1 -= Lq.x * y1[j+0];
        a0 -= Lq.y * y0[j+1]; a1 -= Lq.y * y1[j+1];
        a0 -= Lq.z * y0[j+2]; a1 -= Lq.z * y1[j+2];
        a0 -= Lq.w * y0[j+3]; a1 -= Lq.w * y1[j+3];
      }
#pragma unroll
      for (int j = (i & ~3); j < i; ++j) {
        float l = Ls[i][j];
        a0 -= l * y0[j]; a1 -= l * y1[j];
      }
      float r = rinv_s[i];
      float v0 = a0 * r, v1 = a1 * r;
      y0[i] = v0; y1[i] = v1;
      maha0 += v0 * v0; maha1 += v1 * v1;
    }
    acc += g0 * (0.5f * maha0 + logdet + C0) + g1 * (0.5f * maha1 + logdet + C0);
  }

  float w = waveReduceSum(acc);
  const int lane = tid & 63, wid = tid >> 6;
  if (lane == 0) red[wid] = w;
  __syncthreads();
  if (tid == 0) {
    float ssum = red[0] + red[1] + red[2] + red[3];
    atomicAdd(nll_acc, (double)ssum);
  }
}

__global__ __launch_bounds__(BS) void reg_kernel(
    const float* __restrict__ L_subj, const float* __restrict__ L_pop,
    const float* __restrict__ mu_subj, const float* __restrict__ mu_pop,
    const float* __restrict__ maskf, double* __restrict__ accs,
    int P, int K) {
  const int KDD = K * DD * DD;   // 49152 (quad-divisible)
  const int KD  = K * DD;        // 768  (quad-divisible)
  const long NL4 = (long)P * KDD / 4;
  const long NM4 = (long)P * KD / 4;
  float accL = 0.f, accM = 0.f;
  const long stride = (long)gridDim.x * BS;
  for (long q = (long)blockIdx.x * BS + threadIdx.x; q < NL4 + NM4; q += stride) {
    if (q < NL4) {
      long e = q * 4;
      int p   = (int)(e / KDD);
      int rem = (int)(e % KDD);
      float w = maskf[p];
      float4 a = ((const float4*)L_subj)[q];
      float4 c = *(const float4*)(L_pop + rem);
      float dx = a.x - c.x, dy = a.y - c.y, dz = a.z - c.z, dw = a.w - c.w;
      accL += w * (dx*dx + dy*dy + dz*dz + dw*dw);
    } else {
      long e = (q - NL4) * 4;
      int p   = (int)(e / KD);
      int rem = (int)(e % KD);
      float w = maskf[p];
      float4 a = ((const float4*)mu_subj)[q - NL4];
      float4 c = *(const float4*)(mu_pop + rem);
      float dx = a.x - c.x, dy = a.y - c.y, dz = a.z - c.z, dw = a.w - c.w;
      accM += w * (dx*dx + dy*dy + dz*dz + dw*dw);
    }
  }
  __shared__ float redL[4], redM[4];
  accL = waveReduceSum(accL);
  accM = waveReduceSum(accM);
  const int lane = threadIdx.x & 63, wid = threadIdx.x >> 6;
  if (lane == 0) { redL[wid] = accL; redM[wid] = accM; }
  __syncthreads();
  if (threadIdx.x == 0) {
    atomicAdd(&accs[2], (double)(redL[0] + redL[1] + redL[2] + redL[3]));
    atomicAdd(&accs[1], (double)(redM[0] + redM[1] + redM[2] + redM[3]));
  }
}

__global__ void finalize_kernel(const double* __restrict__ accs,
                                const float* __restrict__ maskf,
                                const int* __restrict__ n_subj,
                                float* __restrict__ out, int P, float n) {
  if (threadIdx.x == 0 && blockIdx.x == 0) {
    float s = 0.f;
    for (int p = 0; p < P; ++p) s += maskf[p];
    double nll = accs[0] / (double)n;
    double reg = ((double)s / (double)(*n_subj)) * (0.05 * accs[1] + 0.05 * accs[2]);
    out[0] = (float)(nll + reg);
  }
}

extern "C" void kernel_launch(void* const* d_in, const int* in_sizes, int n_in,
                              void* d_out, int out_size, void* d_ws, size_t ws_size,
                              hipStream_t stream) {
  const float* x       = (const float*)d_in[0];
  const float* mu_pop  = (const float*)d_in[1];
  const float* L_pop   = (const float*)d_in[2];
  const float* mu_subj = (const float*)d_in[3];
  const float* L_subj  = (const float*)d_in[4];
  const float* gamma   = (const float*)d_in[5];
  const int*   sid     = (const int*)d_in[6];
  const int*   nsub    = (const int*)d_in[7];

  const int B = in_sizes[6];              // 64
  const int K = in_sizes[1] / DD;         // 12
  const int T = in_sizes[0] / (B * DD);   // 512
  const int P = in_sizes[3] / (K * DD);   // 100

  double* accs  = (double*)d_ws;
  float*  maskf = (float*)((char*)d_ws + 32);

  init_kernel<<<1, 256, 0, stream>>>(sid, maskf, accs, B, P);
  nll_kernel<<<B * K, BS, 0, stream>>>(x, mu_subj, L_subj, gamma, sid, accs, T, K);
  reg_kernel<<<1024, BS, 0, stream>>>(L_subj, L_pop, mu_subj, mu_pop, maskf, accs, P, K);
  finalize_kernel<<<1, 64, 0, stream>>>(accs, maskf, nsub, (float*)d_out, P,
                                        (float)(B * T));
}

// Round 4
// 2314.694 us; speedup vs baseline: 1.0427x; 1.0427x over previous
//
#include <hip/hip_runtime.h>
#include <math.h>

// Problem: B=64, T=512, D=64, K=12, P=100
// loss = -sum(gamma * logp)/(B*T) + (s/P)*(0.05*||mu_diff||^2_masked + 0.05*||L_diff||^2_masked)
// logp[b,k,t] = -0.5*||L^-1 (x - mu)||^2 - sum(log diag L) - 0.5*D*log(2pi)
//
// R3 post-mortem: #pragma-unroll substitution spilled y[] to scratch
// (WRITE_SIZE 3.0 GB, VALUBusy 1.5%). This version forces full unroll via
// template recursion: every y[] index is compile-time -> guaranteed VGPRs.

#define DD 64
#define BS 512   // one thread per t; T == 512

__device__ __forceinline__ float waveReduceSum(float v) {
#pragma unroll
  for (int off = 32; off > 0; off >>= 1) v += __shfl_down(v, off, 64);
  return v;
}

// ---- fully-static forward substitution -------------------------------------
// row I: y[I] = (r[I] - sum_{j<I} L[I][j]*y[j]) * rinv[I];  maha += y[I]^2
template <int I>
__device__ __forceinline__ float rowdot(const float (&Ls)[DD][DD], const float (&y)[DD]) {
  float p0 = 0.f, p1 = 0.f, p2 = 0.f, p3 = 0.f;
  constexpr int Q = I >> 2;
#pragma unroll
  for (int q = 0; q < Q; ++q) {          // compile-time trip count
    float4 Lq = *(const float4*)&Ls[I][4 * q];   // ds_read_b128, wave-uniform broadcast
    p0 += Lq.x * y[4 * q + 0];
    p1 += Lq.y * y[4 * q + 1];
    p2 += Lq.z * y[4 * q + 2];
    p3 += Lq.w * y[4 * q + 3];
  }
#pragma unroll
  for (int j = (I & ~3); j < I; ++j) p0 += Ls[I][j] * y[j];  // compile-time bounds
  return (p0 + p1) + (p2 + p3);
}

template <int I>
__device__ __forceinline__ void solve_rows(const float (&Ls)[DD][DD],
                                           const float (&rinv)[DD],
                                           float (&y)[DD], float& maha) {
  if constexpr (I < DD) {
    float v = (y[I] - rowdot<I>(Ls, y)) * rinv[I];
    y[I] = v;
    maha += v * v;
    solve_rows<I + 1>(Ls, rinv, y, maha);
  }
}

// ws layout (bytes):
// [0]  double nll_acc   [8] double mu_acc   [16] double L_acc
// [32] float mask[128]

__global__ void init_kernel(const int* __restrict__ sid, float* __restrict__ maskf,
                            double* __restrict__ accs, int B, int P) {
  int tid = threadIdx.x;
  if (tid < 3) accs[tid] = 0.0;
  if (tid < P) maskf[tid] = 0.0f;
  __syncthreads();
  if (tid < B) maskf[sid[tid]] = 1.0f;  // benign write race, same value
}

__global__ __launch_bounds__(BS) void nll_kernel(
    const float* __restrict__ x, const float* __restrict__ mu_subj,
    const float* __restrict__ L_subj, const float* __restrict__ gamma,
    const int* __restrict__ sid, double* __restrict__ nll_acc,
    int T, int K) {
  __shared__ float Ls[DD][DD];   // 16 KB; all reads are wave-uniform broadcasts
  __shared__ float mu_s[DD];
  __shared__ float rinv_s[DD];
  __shared__ float red[BS / 64];
  __shared__ float logdet_s;

  const int bx = blockIdx.x;
  const int b = bx / K, k = bx % K;
  const int tid = threadIdx.x;
  const int s = sid[b];
  const float* Lg  = L_subj  + ((size_t)s * K + k) * (DD * DD);
  const float* mug = mu_subj + ((size_t)s * K + k) * DD;

  // stage L (4096 floats = 1024 float4; 512 threads -> 2 each) + mu
#pragma unroll
  for (int q = 0; q < 2; ++q) {
    int off = q * (BS * 4) + tid * 4;
    *(float4*)((float*)Ls + off) = *(const float4*)(Lg + off);
  }
  if (tid < DD / 4) ((float4*)mu_s)[tid] = ((const float4*)mug)[tid];
  __syncthreads();

  if (tid < DD) {  // exactly wave 0
    float d = Ls[tid][tid];
    rinv_s[tid] = 1.0f / d;
    float lg = logf(d);
    lg = waveReduceSum(lg);
    if (tid == 0) logdet_s = lg;
  }
  __syncthreads();

  const float C0 = 58.81206612509905f;  // 0.5 * 64 * log(2*pi)
  const float logdet = logdet_s;
  float acc = 0.f;

  for (int t = tid; t < T; t += BS) {   // executes exactly once (T == BS)
    // gamma early: latency hides under the FMA chain
    float g = gamma[((size_t)b * T + t) * K + k];

    float y[DD];
    const float4* xr = (const float4*)(x + ((size_t)b * T + t) * DD);
#pragma unroll
    for (int q = 0; q < DD / 4; ++q) {  // static after unroll -> registers
      float4 a = xr[q];
      float4 m = ((const float4*)mu_s)[q];
      y[4 * q + 0] = a.x - m.x;
      y[4 * q + 1] = a.y - m.y;
      y[4 * q + 2] = a.z - m.z;
      y[4 * q + 3] = a.w - m.w;
    }
    float maha = 0.f;
    solve_rows<0>(Ls, rinv_s, y, maha);
    acc += g * (0.5f * maha + logdet + C0);
  }

  float w = waveReduceSum(acc);
  const int lane = tid & 63, wid = tid >> 6;
  if (lane == 0) red[wid] = w;
  __syncthreads();
  if (tid == 0) {
    float ssum = 0.f;
#pragma unroll
    for (int i = 0; i < BS / 64; ++i) ssum += red[i];
    atomicAdd(nll_acc, (double)ssum);
  }
}

__global__ __launch_bounds__(256) void reg_kernel(
    const float* __restrict__ L_subj, const float* __restrict__ L_pop,
    const float* __restrict__ mu_subj, const float* __restrict__ mu_pop,
    const float* __restrict__ maskf, double* __restrict__ accs,
    int P, int K) {
  const int KDD = K * DD * DD;   // 49152
  const int KD  = K * DD;        // 768
  const long NL4 = (long)P * KDD / 4;
  const long NM4 = (long)P * KD / 4;
  float accL = 0.f, accM = 0.f;
  const long stride = (long)gridDim.x * 256;
  for (long q = (long)blockIdx.x * 256 + threadIdx.x; q < NL4 + NM4; q += stride) {
    if (q < NL4) {
      long e = q * 4;
      int p   = (int)(e / KDD);
      int rem = (int)(e % KDD);
      float w = maskf[p];
      float4 a = ((const float4*)L_subj)[q];
      float4 c = *(const float4*)(L_pop + rem);
      float dx = a.x - c.x, dy = a.y - c.y, dz = a.z - c.z, dw = a.w - c.w;
      accL += w * (dx * dx + dy * dy + dz * dz + dw * dw);
    } else {
      long e = (q - NL4) * 4;
      int p   = (int)(e / KD);
      int rem = (int)(e % KD);
      float w = maskf[p];
      float4 a = ((const float4*)mu_subj)[q - NL4];
      float4 c = *(const float4*)(mu_pop + rem);
      float dx = a.x - c.x, dy = a.y - c.y, dz = a.z - c.z, dw = a.w - c.w;
      accM += w * (dx * dx + dy * dy + dz * dz + dw * dw);
    }
  }
  __shared__ float redL[4], redM[4];
  accL = waveReduceSum(accL);
  accM = waveReduceSum(accM);
  const int lane = threadIdx.x & 63, wid = threadIdx.x >> 6;
  if (lane == 0) { redL[wid] = accL; redM[wid] = accM; }
  __syncthreads();
  if (threadIdx.x == 0) {
    atomicAdd(&accs[2], (double)(redL[0] + redL[1] + redL[2] + redL[3]));
    atomicAdd(&accs[1], (double)(redM[0] + redM[1] + redM[2] + redM[3]));
  }
}

__global__ void finalize_kernel(const double* __restrict__ accs,
                                const float* __restrict__ maskf,
                                const int* __restrict__ n_subj,
                                float* __restrict__ out, int P, float n) {
  if (threadIdx.x == 0 && blockIdx.x == 0) {
    float s = 0.f;
    for (int p = 0; p < P; ++p) s += maskf[p];
    double nll = accs[0] / (double)n;
    double reg = ((double)s / (double)(*n_subj)) * (0.05 * accs[1] + 0.05 * accs[2]);
    out[0] = (float)(nll + reg);
  }
}

extern "C" void kernel_launch(void* const* d_in, const int* in_sizes, int n_in,
                              void* d_out, int out_size, void* d_ws, size_t ws_size,
                              hipStream_t stream) {
  const float* x       = (const float*)d_in[0];
  const float* mu_pop  = (const float*)d_in[1];
  const float* L_pop   = (const float*)d_in[2];
  const float* mu_subj = (const float*)d_in[3];
  const float* L_subj  = (const float*)d_in[4];
  const float* gamma   = (const float*)d_in[5];
  const int*   sid     = (const int*)d_in[6];
  const int*   nsub    = (const int*)d_in[7];

  const int B = in_sizes[6];              // 64
  const int K = in_sizes[1] / DD;         // 12
  const int T = in_sizes[0] / (B * DD);   // 512
  const int P = in_sizes[3] / (K * DD);   // 100

  double* accs  = (double*)d_ws;
  float*  maskf = (float*)((char*)d_ws + 32);

  init_kernel<<<1, 256, 0, stream>>>(sid, maskf, accs, B, P);
  nll_kernel<<<B * K, BS, 0, stream>>>(x, mu_subj, L_subj, gamma, sid, accs, T, K);
  reg_kernel<<<1024, 256, 0, stream>>>(L_subj, L_pop, mu_subj, mu_pop, maskf, accs, P, K);
  finalize_kernel<<<1, 64, 0, stream>>>(accs, maskf, nsub, (float*)d_out, P,
                                        (float)(B * T));
}

// Round 6
// 176.136 us; speedup vs baseline: 13.7023x; 13.1415x over previous
//
#include <hip/hip_runtime.h>
#include <math.h>

// Problem: B=64, T=512, D=64, K=12, P=100
// loss = -sum(gamma * logp)/(B*T) + (s/P)*(0.05*||mu_diff||^2 + 0.05*||L_diff||^2)_masked
// logp[b,k,t] = -0.5*||L^-1 (x - mu)||^2 - sum(log diag L) - 0.5*D*log(2pi)
//
// R3: #pragma-unroll y[64] spilled (WRITE 3.0 GB). R4: template-recursion y[64]
// ALSO spilled (WRITE 3.9 GB, VALUBusy 1.5%). This version eliminates the array
// entirely: y lives in 16 NAMED float4 variables, substitution is macro-generated
// flat code. Named scalars cannot be a memory object -> guaranteed VGPRs.

#define DD 64
#define BS 512  // one thread per t; T == 512

__device__ __forceinline__ float waveReduceSum(float v) {
#pragma unroll
  for (int off = 32; off > 0; off >>= 1) v += __shfl_down(v, off, 64);
  return v;
}

// ws layout (bytes): [0] double nll_acc  [8] double mu_acc  [16] double L_acc
//                    [32] float mask[128]

__global__ void init_kernel(const int* __restrict__ sid, float* __restrict__ maskf,
                            double* __restrict__ accs, int B, int P) {
  int tid = threadIdx.x;
  if (tid < 3) accs[tid] = 0.0;
  if (tid < P) maskf[tid] = 0.0f;
  __syncthreads();
  if (tid < B) maskf[sid[tid]] = 1.0f;  // benign write race, same value
}

// ---- macro-generated, fully register-resident forward substitution ---------
#define LS4(I, Q) (*(const float4*)&Ls[(I)][4 * (Q)])

// acc -= dot(L[I][4Q..4Q+3], vQ)  — serial FMA chain, contracts to v_fmac_f32
#define FMAQ(Q, I)                      \
  {                                     \
    float4 Lq = LS4(I, Q);              \
    acc -= Lq.x * v##Q.x;               \
    acc -= Lq.y * v##Q.y;               \
    acc -= Lq.z * v##Q.z;               \
    acc -= Lq.w * v##Q.w;               \
  }

#define DOT0(I)
#define DOT1(I) DOT0(I) FMAQ(0, I)
#define DOT2(I) DOT1(I) FMAQ(1, I)
#define DOT3(I) DOT2(I) FMAQ(2, I)
#define DOT4(I) DOT3(I) FMAQ(3, I)
#define DOT5(I) DOT4(I) FMAQ(4, I)
#define DOT6(I) DOT5(I) FMAQ(5, I)
#define DOT7(I) DOT6(I) FMAQ(6, I)
#define DOT8(I) DOT7(I) FMAQ(7, I)
#define DOT9(I) DOT8(I) FMAQ(8, I)
#define DOT10(I) DOT9(I) FMAQ(9, I)
#define DOT11(I) DOT10(I) FMAQ(10, I)
#define DOT12(I) DOT11(I) FMAQ(11, I)
#define DOT13(I) DOT12(I) FMAQ(12, I)
#define DOT14(I) DOT13(I) FMAQ(13, I)
#define DOT15(I) DOT14(I) FMAQ(14, I)

#define ROWX(A)                                   \
  {                                               \
    float acc = v##A.x;                           \
    DOT##A(4 * A)                                 \
    float val = acc * rinv_s[4 * A];              \
    v##A.x = val;                                 \
    maha += val * val;                            \
  }
#define ROWY(A)                                   \
  {                                               \
    float acc = v##A.y;                           \
    DOT##A(4 * A + 1)                             \
    acc -= Ls[4 * A + 1][4 * A] * v##A.x;         \
    float val = acc * rinv_s[4 * A + 1];          \
    v##A.y = val;                                 \
    maha += val * val;                            \
  }
#define ROWZ(A)                                   \
  {                                               \
    float acc = v##A.z;                           \
    DOT##A(4 * A + 2)                             \
    acc -= Ls[4 * A + 2][4 * A] * v##A.x;         \
    acc -= Ls[4 * A + 2][4 * A + 1] * v##A.y;     \
    float val = acc * rinv_s[4 * A + 2];          \
    v##A.z = val;                                 \
    maha += val * val;                            \
  }
#define ROWW(A)                                   \
  {                                               \
    float acc = v##A.w;                           \
    DOT##A(4 * A + 3)                             \
    acc -= Ls[4 * A + 3][4 * A] * v##A.x;         \
    acc -= Ls[4 * A + 3][4 * A + 1] * v##A.y;     \
    acc -= Ls[4 * A + 3][4 * A + 2] * v##A.z;     \
    float val = acc * rinv_s[4 * A + 3];          \
    v##A.w = val;                                 \
    maha += val * val;                            \
  }
#define QUAD(A) ROWX(A) ROWY(A) ROWZ(A) ROWW(A)

#define LOADQ(Q)                                  \
  {                                               \
    float4 a = xr[Q];                             \
    float4 m = ((const float4*)mu_s)[Q];          \
    v##Q.x = a.x - m.x;                           \
    v##Q.y = a.y - m.y;                           \
    v##Q.z = a.z - m.z;                           \
    v##Q.w = a.w - m.w;                           \
  }

__global__ __launch_bounds__(BS) void nll_kernel(
    const float* __restrict__ x, const float* __restrict__ mu_subj,
    const float* __restrict__ L_subj, const float* __restrict__ gamma,
    const int* __restrict__ sid, double* __restrict__ nll_acc,
    int T, int K) {
  __shared__ float Ls[DD][DD];  // 16 KB; all reads are wave-uniform broadcasts
  __shared__ float mu_s[DD];
  __shared__ float rinv_s[DD];
  __shared__ float red[BS / 64];
  __shared__ float logdet_s;

  const int bx = blockIdx.x;
  const int b = bx / K, k = bx % K;
  const int tid = threadIdx.x;
  const int s = sid[b];
  const float* Lg = L_subj + ((size_t)s * K + k) * (DD * DD);
  const float* mug = mu_subj + ((size_t)s * K + k) * DD;

  // stage L (4096 floats = 1024 float4; 512 threads -> 2 each) + mu
#pragma unroll
  for (int q = 0; q < 2; ++q) {
    int off = q * (BS * 4) + tid * 4;
    *(float4*)((float*)Ls + off) = *(const float4*)(Lg + off);
  }
  if (tid < DD / 4) ((float4*)mu_s)[tid] = ((const float4*)mug)[tid];
  __syncthreads();

  if (tid < DD) {  // exactly wave 0
    float d = Ls[tid][tid];
    rinv_s[tid] = 1.0f / d;
    float lg = logf(d);
    lg = waveReduceSum(lg);
    if (tid == 0) logdet_s = lg;
  }
  __syncthreads();

  const float C0 = 58.81206612509905f;  // 0.5 * 64 * log(2*pi)
  const float logdet = logdet_s;

  const int t = tid;  // T == BS: exactly one t per thread
  // gamma early: HBM/L2 latency hides under the FMA chain
  const float g = gamma[((size_t)b * T + t) * K + k];

  const float4* xr = (const float4*)(x + ((size_t)b * T + t) * DD);
  float4 v0, v1, v2, v3, v4, v5, v6, v7, v8, v9, v10, v11, v12, v13, v14, v15;
  LOADQ(0) LOADQ(1) LOADQ(2) LOADQ(3) LOADQ(4) LOADQ(5) LOADQ(6) LOADQ(7)
  LOADQ(8) LOADQ(9) LOADQ(10) LOADQ(11) LOADQ(12) LOADQ(13) LOADQ(14) LOADQ(15)

  float maha = 0.f;
  QUAD(0) QUAD(1) QUAD(2) QUAD(3) QUAD(4) QUAD(5) QUAD(6) QUAD(7)
  QUAD(8) QUAD(9) QUAD(10) QUAD(11) QUAD(12) QUAD(13) QUAD(14) QUAD(15)

  float acc = g * (0.5f * maha + logdet + C0);

  float w = waveReduceSum(acc);
  const int lane = tid & 63, wid = tid >> 6;
  if (lane == 0) red[wid] = w;
  __syncthreads();
  if (tid == 0) {
    float ssum = 0.f;
#pragma unroll
    for (int i = 0; i < BS / 64; ++i) ssum += red[i];
    atomicAdd(nll_acc, (double)ssum);
  }
}

__global__ __launch_bounds__(256) void reg_kernel(
    const float* __restrict__ L_subj, const float* __restrict__ L_pop,
    const float* __restrict__ mu_subj, const float* __restrict__ mu_pop,
    const float* __restrict__ maskf, double* __restrict__ accs,
    int P, int K) {
  const int KDD = K * DD * DD;  // 49152
  const int KD = K * DD;        // 768
  const long NL4 = (long)P * KDD / 4;
  const long NM4 = (long)P * KD / 4;
  float accL = 0.f, accM = 0.f;
  const long stride = (long)gridDim.x * 256;
  for (long q = (long)blockIdx.x * 256 + threadIdx.x; q < NL4 + NM4; q += stride) {
    if (q < NL4) {
      long e = q * 4;
      int p = (int)(e / KDD);
      int rem = (int)(e % KDD);
      float w = maskf[p];
      float4 a = ((const float4*)L_subj)[q];
      float4 c = *(const float4*)(L_pop + rem);
      float dx = a.x - c.x, dy = a.y - c.y, dz = a.z - c.z, dw = a.w - c.w;
      accL += w * (dx * dx + dy * dy + dz * dz + dw * dw);
    } else {
      long e = (q - NL4) * 4;
      int p = (int)(e / KD);
      int rem = (int)(e % KD);
      float w = maskf[p];
      float4 a = ((const float4*)mu_subj)[q - NL4];
      float4 c = *(const float4*)(mu_pop + rem);
      float dx = a.x - c.x, dy = a.y - c.y, dz = a.z - c.z, dw = a.w - c.w;
      accM += w * (dx * dx + dy * dy + dz * dz + dw * dw);
    }
  }
  __shared__ float redL[4], redM[4];
  accL = waveReduceSum(accL);
  accM = waveReduceSum(accM);
  const int lane = threadIdx.x & 63, wid = threadIdx.x >> 6;
  if (lane == 0) { redL[wid] = accL; redM[wid] = accM; }
  __syncthreads();
  if (threadIdx.x == 0) {
    atomicAdd(&accs[2], (double)(redL[0] + redL[1] + redL[2] + redL[3]));
    atomicAdd(&accs[1], (double)(redM[0] + redM[1] + redM[2] + redM[3]));
  }
}

__global__ void finalize_kernel(const double* __restrict__ accs,
                                const float* __restrict__ maskf,
                                const int* __restrict__ n_subj,
                                float* __restrict__ out, int P, float n) {
  if (threadIdx.x == 0 && blockIdx.x == 0) {
    float s = 0.f;
    for (int p = 0; p < P; ++p) s += maskf[p];
    double nll = accs[0] / (double)n;
    double reg = ((double)s / (double)(*n_subj)) * (0.05 * accs[1] + 0.05 * accs[2]);
    out[0] = (float)(nll + reg);
  }
}

extern "C" void kernel_launch(void* const* d_in, const int* in_sizes, int n_in,
                              void* d_out, int out_size, void* d_ws, size_t ws_size,
                              hipStream_t stream) {
  const float* x = (const float*)d_in[0];
  const float* mu_pop = (const float*)d_in[1];
  const float* L_pop = (const float*)d_in[2];
  const float* mu_subj = (const float*)d_in[3];
  const float* L_subj = (const float*)d_in[4];
  const float* gamma = (const float*)d_in[5];
  const int* sid = (const int*)d_in[6];
  const int* nsub = (const int*)d_in[7];

  const int B = in_sizes[6];             // 64
  const int K = in_sizes[1] / DD;        // 12
  const int T = in_sizes[0] / (B * DD);  // 512
  const int P = in_sizes[3] / (K * DD);  // 100

  double* accs = (double*)d_ws;
  float* maskf = (float*)((char*)d_ws + 32);

  init_kernel<<<1, 256, 0, stream>>>(sid, maskf, accs, B, P);
  nll_kernel<<<B * K, BS, 0, stream>>>(x, mu_subj, L_subj, gamma, sid, accs, T, K);
  reg_kernel<<<1024, 256, 0, stream>>>(L_subj, L_pop, mu_subj, mu_pop, maskf, accs, P, K);
  finalize_kernel<<<1, 64, 0, stream>>>(accs, maskf, nsub, (float*)d_out, P,
                                        (float)(B * T));
}

// Round 10
// 159.631 us; speedup vs baseline: 15.1191x; 1.1034x over previous
//
#include <hip/hip_runtime.h>
#include <math.h>

// Problem: B=64, T=512, D=64, K=12, P=100
// loss = -sum(gamma * logp)/(B*T) + (s/P)*(0.05*||mu_diff||^2 + 0.05*||L_diff||^2)_masked
// logp[b,k,t] = -0.5*||L^-1 (x - mu)||^2 - sum(log diag L) - 0.5*D*log(2pi)
//
// R6 post-mortem: spill fixed (WRITE 24 KB) but dur=67.8us was LDS-issue-bound:
// 520 wave-uniform ds_read_b128 broadcasts/wave deliver 16B per 1024B-slot
// (24 waves/CU x 520 x ~12cyc = 62us ~= measured). Fix: L and mu are
// block-uniform -> read straight from GLOBAL with uniform addresses so the
// compiler emits s_load (scalar cache, SGPR operands into v_fma). LDS now only
// holds rinv/logdet/reduction (~35 LDS instrs/thread).

#define DD 64
#define BS 512  // one thread per t; T == 512

__device__ __forceinline__ float waveReduceSum(float v) {
#pragma unroll
  for (int off = 32; off > 0; off >>= 1) v += __shfl_down(v, off, 64);
  return v;
}

// ws layout (bytes): [0] double nll_acc  [8] double mu_acc  [16] double L_acc
//                    [32] float mask[128]

__global__ void init_kernel(const int* __restrict__ sid, float* __restrict__ maskf,
                            double* __restrict__ accs, int B, int P) {
  int tid = threadIdx.x;
  if (tid < 3) accs[tid] = 0.0;
  if (tid < P) maskf[tid] = 0.0f;
  __syncthreads();
  if (tid < B) maskf[sid[tid]] = 1.0f;  // benign write race, same value
}

// ---- register-resident substitution, L streamed via scalar loads -----------
// LQ4(I,Q): float4 L[I][4Q..4Q+3], wave-uniform address -> s_load_dwordx4
#define LQ4(I, Q) (*(const float4*)(Lg + (I) * DD + 4 * (Q)))

// acc -= dot(L[I][4Q..4Q+3], vQ)  — serial FMA chain, SGPR x VGPR operands
#define FMAQ(Q, I)                      \
  {                                     \
    float4 Lq = LQ4(I, Q);              \
    acc -= Lq.x * v##Q.x;               \
    acc -= Lq.y * v##Q.y;               \
    acc -= Lq.z * v##Q.z;               \
    acc -= Lq.w * v##Q.w;               \
  }

#define DOT0(I)
#define DOT1(I) DOT0(I) FMAQ(0, I)
#define DOT2(I) DOT1(I) FMAQ(1, I)
#define DOT3(I) DOT2(I) FMAQ(2, I)
#define DOT4(I) DOT3(I) FMAQ(3, I)
#define DOT5(I) DOT4(I) FMAQ(4, I)
#define DOT6(I) DOT5(I) FMAQ(5, I)
#define DOT7(I) DOT6(I) FMAQ(6, I)
#define DOT8(I) DOT7(I) FMAQ(7, I)
#define DOT9(I) DOT8(I) FMAQ(8, I)
#define DOT10(I) DOT9(I) FMAQ(9, I)
#define DOT11(I) DOT10(I) FMAQ(10, I)
#define DOT12(I) DOT11(I) FMAQ(11, I)
#define DOT13(I) DOT12(I) FMAQ(12, I)
#define DOT14(I) DOT13(I) FMAQ(13, I)
#define DOT15(I) DOT14(I) FMAQ(14, I)

// Intra-quad tail terms come from the same uniform float4 row-quad load
// (unused upper components are junk-but-loaded; diagonal handled via rinv).
#define ROWX(A)                                   \
  {                                               \
    float acc = v##A.x;                           \
    DOT##A(4 * A)                                 \
    float val = acc * rq.x;                       \
    v##A.x = val;                                 \
    maha += val * val;                            \
  }
#define ROWY(A)                                   \
  {                                               \
    float acc = v##A.y;                           \
    DOT##A(4 * A + 1)                             \
    float4 tq = LQ4(4 * A + 1, A);                \
    acc -= tq.x * v##A.x;                         \
    float val = acc * rq.y;                       \
    v##A.y = val;                                 \
    maha += val * val;                            \
  }
#define ROWZ(A)                                   \
  {                                               \
    float acc = v##A.z;                           \
    DOT##A(4 * A + 2)                             \
    float4 tq = LQ4(4 * A + 2, A);                \
    acc -= tq.x * v##A.x;                         \
    acc -= tq.y * v##A.y;                         \
    float val = acc * rq.z;                       \
    v##A.z = val;                                 \
    maha += val * val;                            \
  }
#define ROWW(A)                                   \
  {                                               \
    float acc = v##A.w;                           \
    DOT##A(4 * A + 3)                             \
    float4 tq = LQ4(4 * A + 3, A);                \
    acc -= tq.x * v##A.x;                         \
    acc -= tq.y * v##A.y;                         \
    acc -= tq.z * v##A.z;                         \
    float val = acc * rq.w;                       \
    v##A.w = val;                                 \
    maha += val * val;                            \
  }
#define QUAD(A)                                   \
  {                                               \
    float4 rq = *(const float4*)&rinv_s[4 * A];   \
    ROWX(A) ROWY(A) ROWZ(A) ROWW(A)               \
  }

#define LOADQ(Q)                                  \
  {                                               \
    float4 a = xr[Q];                             \
    float4 m = *(const float4*)(mug + 4 * (Q));   \
    v##Q.x = a.x - m.x;                           \
    v##Q.y = a.y - m.y;                           \
    v##Q.z = a.z - m.z;                           \
    v##Q.w = a.w - m.w;                           \
  }

__global__ __launch_bounds__(BS) void nll_kernel(
    const float* __restrict__ x, const float* __restrict__ mu_subj,
    const float* __restrict__ L_subj, const float* __restrict__ gamma,
    const int* __restrict__ sid, double* __restrict__ nll_acc,
    int T, int K) {
  __shared__ float rinv_s[DD];
  __shared__ float red[BS / 64];
  __shared__ float logdet_s;

  const int bx = blockIdx.x;
  const int b = bx / K, k = bx % K;
  const int tid = threadIdx.x;
  // force the subject id (and thus L/mu bases) into an SGPR -> scalar loads
  const int s = __builtin_amdgcn_readfirstlane(sid[b]);
  const float* Lg  = L_subj  + ((size_t)s * K + k) * (DD * DD);
  const float* mug = mu_subj + ((size_t)s * K + k) * DD;

  if (tid < DD) {  // exactly wave 0: rinv + logdet from the diagonal
    float d = Lg[tid * DD + tid];
    rinv_s[tid] = 1.0f / d;
    float lg = logf(d);
    lg = waveReduceSum(lg);
    if (tid == 0) logdet_s = lg;
  }
  __syncthreads();

  const float C0 = 58.81206612509905f;  // 0.5 * 64 * log(2*pi)
  const float logdet = logdet_s;

  const int t = tid;  // T == BS: exactly one t per thread
  // gamma early: HBM/L2 latency hides under the FMA chain
  const float g = gamma[((size_t)b * T + t) * K + k];

  const float4* xr = (const float4*)(x + ((size_t)b * T + t) * DD);
  float4 v0, v1, v2, v3, v4, v5, v6, v7, v8, v9, v10, v11, v12, v13, v14, v15;
  LOADQ(0) LOADQ(1) LOADQ(2) LOADQ(3) LOADQ(4) LOADQ(5) LOADQ(6) LOADQ(7)
  LOADQ(8) LOADQ(9) LOADQ(10) LOADQ(11) LOADQ(12) LOADQ(13) LOADQ(14) LOADQ(15)

  float maha = 0.f;
  QUAD(0) QUAD(1) QUAD(2) QUAD(3) QUAD(4) QUAD(5) QUAD(6) QUAD(7)
  QUAD(8) QUAD(9) QUAD(10) QUAD(11) QUAD(12) QUAD(13) QUAD(14) QUAD(15)

  float acc = g * (0.5f * maha + logdet + C0);

  float w = waveReduceSum(acc);
  const int lane = tid & 63, wid = tid >> 6;
  if (lane == 0) red[wid] = w;
  __syncthreads();
  if (tid == 0) {
    float ssum = 0.f;
#pragma unroll
    for (int i = 0; i < BS / 64; ++i) ssum += red[i];
    atomicAdd(nll_acc, (double)ssum);
  }
}

__global__ __launch_bounds__(256) void reg_kernel(
    const float* __restrict__ L_subj, const float* __restrict__ L_pop,
    const float* __restrict__ mu_subj, const float* __restrict__ mu_pop,
    const float* __restrict__ maskf, double* __restrict__ accs,
    int P, int K) {
  const int KDD = K * DD * DD;  // 49152
  const int KD = K * DD;        // 768
  const long NL4 = (long)P * KDD / 4;
  const long NM4 = (long)P * KD / 4;
  float accL = 0.f, accM = 0.f;
  const long stride = (long)gridDim.x * 256;
  for (long q = (long)blockIdx.x * 256 + threadIdx.x; q < NL4 + NM4; q += stride) {
    if (q < NL4) {
      long e = q * 4;
      int p = (int)(e / KDD);
      int rem = (int)(e % KDD);
      float w = maskf[p];
      float4 a = ((const float4*)L_subj)[q];
      float4 c = *(const float4*)(L_pop + rem);
      float dx = a.x - c.x, dy = a.y - c.y, dz = a.z - c.z, dw = a.w - c.w;
      accL += w * (dx * dx + dy * dy + dz * dz + dw * dw);
    } else {
      long e = (q - NL4) * 4;
      int p = (int)(e / KD);
      int rem = (int)(e % KD);
      float w = maskf[p];
      float4 a = ((const float4*)mu_subj)[q - NL4];
      float4 c = *(const float4*)(mu_pop + rem);
      float dx = a.x - c.x, dy = a.y - c.y, dz = a.z - c.z, dw = a.w - c.w;
      accM += w * (dx * dx + dy * dy + dz * dz + dw * dw);
    }
  }
  __shared__ float redL[4], redM[4];
  accL = waveReduceSum(accL);
  accM = waveReduceSum(accM);
  const int lane = threadIdx.x & 63, wid = threadIdx.x >> 6;
  if (lane == 0) { redL[wid] = accL; redM[wid] = accM; }
  __syncthreads();
  if (threadIdx.x == 0) {
    atomicAdd(&accs[2], (double)(redL[0] + redL[1] + redL[2] + redL[3]));
    atomicAdd(&accs[1], (double)(redM[0] + redM[1] + redM[2] + redM[3]));
  }
}

__global__ void finalize_kernel(const double* __restrict__ accs,
                                const float* __restrict__ maskf,
                                const int* __restrict__ n_subj,
                                float* __restrict__ out, int P, float n) {
  if (threadIdx.x == 0 && blockIdx.x == 0) {
    float s = 0.f;
    for (int p = 0; p < P; ++p) s += maskf[p];
    double nll = accs[0] / (double)n;
    double reg = ((double)s / (double)(*n_subj)) * (0.05 * accs[1] + 0.05 * accs[2]);
    out[0] = (float)(nll + reg);
  }
}

extern "C" void kernel_launch(void* const* d_in, const int* in_sizes, int n_in,
                              void* d_out, int out_size, void* d_ws, size_t ws_size,
                              hipStream_t stream) {
  const float* x = (const float*)d_in[0];
  const float* mu_pop = (const float*)d_in[1];
  const float* L_pop = (const float*)d_in[2];
  const float* mu_subj = (const float*)d_in[3];
  const float* L_subj = (const float*)d_in[4];
  const float* gamma = (const float*)d_in[5];
  const int* sid = (const int*)d_in[6];
  const int* nsub = (const int*)d_in[7];

  const int B = in_sizes[6];             // 64
  const int K = in_sizes[1] / DD;        // 12
  const int T = in_sizes[0] / (B * DD);  // 512
  const int P = in_sizes[3] / (K * DD);  // 100

  double* accs = (double*)d_ws;
  float* maskf = (float*)((char*)d_ws + 32);

  init_kernel<<<1, 256, 0, stream>>>(sid, maskf, accs, B, P);
  nll_kernel<<<B * K, BS, 0, stream>>>(x, mu_subj, L_subj, gamma, sid, accs, T, K);
  reg_kernel<<<1024, 256, 0, stream>>>(L_subj, L_pop, mu_subj, mu_pop, maskf, accs, P, K);
  finalize_kernel<<<1, 64, 0, stream>>>(accs, maskf, nsub, (float*)d_out, P,
                                        (float)(B * T));
}

// Round 12
// 131.638 us; speedup vs baseline: 18.3341x; 1.2127x over previous
//
#include <hip/hip_runtime.h>
#include <math.h>

// B=64, T=512, D=64, K=12, P=100
// R10 post-mortem: scalar-load path confirmed (SGPR 112, LDS 512B) but
// SMEM-bound: 530 s_loads/wave serve only 4 FMAs each -> VALUBusy 36%.
// This round: (a) 2-t register tiling: one L-quad s_load feeds 8 FMAs
// (halves SMEM ops per unit work); (b) 4 kernels -> 2 (partial sums, no
// atomics, no init kernel); (c) k-major block map: same-b blocks on same
// XCD (b = bx%64, 64%8==0) for gamma/x L2 locality.

#define DD 64
#define BS 256  // 2 t's per thread; T == 512 == 2*BS

__device__ __forceinline__ float waveReduceSum(float v) {
#pragma unroll
  for (int off = 32; off > 0; off >>= 1) v += __shfl_down(v, off, 64);
  return v;
}
__device__ __forceinline__ double waveReduceSumD(double v) {
#pragma unroll
  for (int off = 32; off > 0; off >>= 1) v += __shfl_down(v, off, 64);
  return v;
}

// ws layout (floats): [0..768) nll_part  [768..768+P) regL_part
//                     [896..896+P) regM_part   (all plain stores, no init)
#define REGL_OFF 768
#define REGM_OFF 896

// ---- 2-t register-resident substitution, L via wave-uniform scalar loads ---
#define LQ4(I, Q) (*(const float4*)(Lg + (I) * DD + 4 * (Q)))

// one uniform L-quad load feeds BOTH t-accumulators: 8 FMAs per s_load
#define FMAQ2(Q, I)                     \
  {                                     \
    float4 Lq = LQ4(I, Q);              \
    a0 -= Lq.x * v##Q.x; a1 -= Lq.x * w##Q.x; \
    a0 -= Lq.y * v##Q.y; a1 -= Lq.y * w##Q.y; \
    a0 -= Lq.z * v##Q.z; a1 -= Lq.z * w##Q.z; \
    a0 -= Lq.w * v##Q.w; a1 -= Lq.w * w##Q.w; \
  }

#define DOT0(I)
#define DOT1(I) DOT0(I) FMAQ2(0, I)
#define DOT2(I) DOT1(I) FMAQ2(1, I)
#define DOT3(I) DOT2(I) FMAQ2(2, I)
#define DOT4(I) DOT3(I) FMAQ2(3, I)
#define DOT5(I) DOT4(I) FMAQ2(4, I)
#define DOT6(I) DOT5(I) FMAQ2(5, I)
#define DOT7(I) DOT6(I) FMAQ2(6, I)
#define DOT8(I) DOT7(I) FMAQ2(7, I)
#define DOT9(I) DOT8(I) FMAQ2(8, I)
#define DOT10(I) DOT9(I) FMAQ2(9, I)
#define DOT11(I) DOT10(I) FMAQ2(10, I)
#define DOT12(I) DOT11(I) FMAQ2(11, I)
#define DOT13(I) DOT12(I) FMAQ2(12, I)
#define DOT14(I) DOT13(I) FMAQ2(13, I)
#define DOT15(I) DOT14(I) FMAQ2(14, I)

#define ROWX2(A)                                  \
  {                                               \
    float a0 = v##A.x, a1 = w##A.x;               \
    DOT##A(4 * A)                                 \
    float u0 = a0 * rq.x, u1 = a1 * rq.x;         \
    v##A.x = u0; w##A.x = u1;                     \
    maha0 += u0 * u0; maha1 += u1 * u1;           \
  }
#define ROWY2(A)                                  \
  {                                               \
    float a0 = v##A.y, a1 = w##A.y;               \
    DOT##A(4 * A + 1)                             \
    float4 tq = LQ4(4 * A + 1, A);                \
    a0 -= tq.x * v##A.x; a1 -= tq.x * w##A.x;     \
    float u0 = a0 * rq.y, u1 = a1 * rq.y;         \
    v##A.y = u0; w##A.y = u1;                     \
    maha0 += u0 * u0; maha1 += u1 * u1;           \
  }
#define ROWZ2(A)                                  \
  {                                               \
    float a0 = v##A.z, a1 = w##A.z;               \
    DOT##A(4 * A + 2)                             \
    float4 tq = LQ4(4 * A + 2, A);                \
    a0 -= tq.x * v##A.x; a1 -= tq.x * w##A.x;     \
    a0 -= tq.y * v##A.y; a1 -= tq.y * w##A.y;     \
    float u0 = a0 * rq.z, u1 = a1 * rq.z;         \
    v##A.z = u0; w##A.z = u1;                     \
    maha0 += u0 * u0; maha1 += u1 * u1;           \
  }
#define ROWW2(A)                                  \
  {                                               \
    float a0 = v##A.w, a1 = w##A.w;               \
    DOT##A(4 * A + 3)                             \
    float4 tq = LQ4(4 * A + 3, A);                \
    a0 -= tq.x * v##A.x; a1 -= tq.x * w##A.x;     \
    a0 -= tq.y * v##A.y; a1 -= tq.y * w##A.y;     \
    a0 -= tq.z * v##A.z; a1 -= tq.z * w##A.z;     \
    float u0 = a0 * rq.w, u1 = a1 * rq.w;         \
    v##A.w = u0; w##A.w = u1;                     \
    maha0 += u0 * u0; maha1 += u1 * u1;           \
  }
#define QUAD2(A)                                  \
  {                                               \
    float4 rq = *(const float4*)&rinv_s[4 * A];   \
    ROWX2(A) ROWY2(A) ROWZ2(A) ROWW2(A)           \
  }

#define LOADQ2(Q)                                 \
  {                                               \
    float4 xa = xr0[Q], xb = xr1[Q];              \
    float4 m = *(const float4*)(mug + 4 * (Q));   \
    v##Q.x = xa.x - m.x; w##Q.x = xb.x - m.x;     \
    v##Q.y = xa.y - m.y; w##Q.y = xb.y - m.y;     \
    v##Q.z = xa.z - m.z; w##Q.z = xb.z - m.z;     \
    v##Q.w = xa.w - m.w; w##Q.w = xb.w - m.w;     \
  }

__global__ __launch_bounds__(BS) void main_kernel(
    const float* __restrict__ x, const float* __restrict__ mu_pop,
    const float* __restrict__ L_pop, const float* __restrict__ mu_subj,
    const float* __restrict__ L_subj, const float* __restrict__ gamma,
    const int* __restrict__ sid, float* __restrict__ part,
    int B, int T, int K, int P) {
  __shared__ float rinv_s[DD];
  __shared__ float redA[BS / 64], redB[BS / 64];
  __shared__ float logdet_s;
  __shared__ int present_s;

  const int bx = blockIdx.x;
  const int tid = threadIdx.x;
  const int lane = tid & 63, wid = tid >> 6;
  const int NB = B * K;  // 768

  if (bx < NB) {
    // ---- NLL block: k-major map (same-b blocks share XCD; B % 8 == 0) ----
    const int b = bx % B;
    const int k = bx / B;
    const int s = __builtin_amdgcn_readfirstlane(sid[b]);
    const float* Lg  = L_subj  + ((size_t)s * K + k) * (DD * DD);
    const float* mug = mu_subj + ((size_t)s * K + k) * DD;

    if (tid < DD) {  // wave 0: rinv + logdet from the diagonal
      float d = Lg[tid * DD + tid];
      rinv_s[tid] = 1.0f / d;
      float lg = logf(d);
      lg = waveReduceSum(lg);
      if (tid == 0) logdet_s = lg;
    }
    __syncthreads();

    const float C0 = 58.81206612509905f;  // 0.5 * 64 * log(2*pi)
    const float logdet = logdet_s;

    const int t0 = tid, t1 = tid + BS;  // T == 2*BS
    const float g0 = gamma[((size_t)b * T + t0) * K + k];
    const float g1 = gamma[((size_t)b * T + t1) * K + k];

    const float4* xr0 = (const float4*)(x + ((size_t)b * T + t0) * DD);
    const float4* xr1 = (const float4*)(x + ((size_t)b * T + t1) * DD);
    float4 v0, v1, v2, v3, v4, v5, v6, v7, v8, v9, v10, v11, v12, v13, v14, v15;
    float4 w0, w1, w2, w3, w4, w5, w6, w7, w8, w9, w10, w11, w12, w13, w14, w15;
    LOADQ2(0) LOADQ2(1) LOADQ2(2) LOADQ2(3) LOADQ2(4) LOADQ2(5) LOADQ2(6) LOADQ2(7)
    LOADQ2(8) LOADQ2(9) LOADQ2(10) LOADQ2(11) LOADQ2(12) LOADQ2(13) LOADQ2(14) LOADQ2(15)

    float maha0 = 0.f, maha1 = 0.f;
    QUAD2(0) QUAD2(1) QUAD2(2) QUAD2(3) QUAD2(4) QUAD2(5) QUAD2(6) QUAD2(7)
    QUAD2(8) QUAD2(9) QUAD2(10) QUAD2(11) QUAD2(12) QUAD2(13) QUAD2(14) QUAD2(15)

    float acc = g0 * (0.5f * maha0 + logdet + C0) + g1 * (0.5f * maha1 + logdet + C0);
    float wsum = waveReduceSum(acc);
    if (lane == 0) redA[wid] = wsum;
    __syncthreads();
    if (tid == 0) part[bx] = redA[0] + redA[1] + redA[2] + redA[3];
  } else {
    // ---- regularizer block: one subject p ----
    const int p = bx - NB;
    if (tid < 64) {  // wave 0: presence check
      int pr = (tid < B) ? (sid[tid] == p) : 0;
      unsigned long long m = __ballot(pr);
      if (tid == 0) present_s = (m != 0ULL);
    }
    __syncthreads();

    float accL = 0.f, accM = 0.f;
    if (present_s) {
      const int KDD4 = K * DD * DD / 4;  // 12288
      const float4* As = (const float4*)(L_subj + (size_t)p * K * DD * DD);
      const float4* Ap = (const float4*)L_pop;
      for (int i = tid; i < KDD4; i += BS) {
        float4 a = As[i], c = Ap[i];
        float dx = a.x - c.x, dy = a.y - c.y, dz = a.z - c.z, dw = a.w - c.w;
        accL += dx * dx + dy * dy + dz * dz + dw * dw;
      }
      const int KD4 = K * DD / 4;  // 192
      const float4* Ms = (const float4*)(mu_subj + (size_t)p * K * DD);
      const float4* Mp = (const float4*)mu_pop;
      for (int i = tid; i < KD4; i += BS) {
        float4 a = Ms[i], c = Mp[i];
        float dx = a.x - c.x, dy = a.y - c.y, dz = a.z - c.z, dw = a.w - c.w;
        accM += dx * dx + dy * dy + dz * dz + dw * dw;
      }
    }
    float l = waveReduceSum(accL), m2 = waveReduceSum(accM);
    if (lane == 0) { redA[wid] = l; redB[wid] = m2; }
    __syncthreads();
    if (tid == 0) {
      part[REGL_OFF + p] = redA[0] + redA[1] + redA[2] + redA[3];
      part[REGM_OFF + p] = redB[0] + redB[1] + redB[2] + redB[3];
    }
  }
}

__global__ __launch_bounds__(256) void finalize_kernel(
    const float* __restrict__ part, const int* __restrict__ sid,
    const int* __restrict__ n_subj, float* __restrict__ out,
    int B, int K, int P, float n) {
  const int NB = B * K;
  const int tid = threadIdx.x;
  const int lane = tid & 63, wid = tid >> 6;
  __shared__ double rd[4][4];
  __shared__ int pres[128];

  double dn = 0.0, dl = 0.0, dm = 0.0, ds = 0.0;
  for (int i = tid; i < NB; i += 256) dn += (double)part[i];
  if (tid < P) {
    dl = (double)part[REGL_OFF + tid];
    dm = (double)part[REGM_OFF + tid];
  }
  if (tid < 128) pres[tid] = 0;
  __syncthreads();
  if (tid < B) pres[sid[tid]] = 1;
  __syncthreads();
  if (tid < P) ds = (double)pres[tid];

  dn = waveReduceSumD(dn); dl = waveReduceSumD(dl);
  dm = waveReduceSumD(dm); ds = waveReduceSumD(ds);
  if (lane == 0) { rd[0][wid] = dn; rd[1][wid] = dl; rd[2][wid] = dm; rd[3][wid] = ds; }
  __syncthreads();
  if (tid == 0) {
    double tn = rd[0][0] + rd[0][1] + rd[0][2] + rd[0][3];
    double tl = rd[1][0] + rd[1][1] + rd[1][2] + rd[1][3];
    double tm = rd[2][0] + rd[2][1] + rd[2][2] + rd[2][3];
    double ts = rd[3][0] + rd[3][1] + rd[3][2] + rd[3][3];
    double nll = tn / (double)n;
    double reg = (ts / (double)(*n_subj)) * (0.05 * tm + 0.05 * tl);
    out[0] = (float)(nll + reg);
  }
}

extern "C" void kernel_launch(void* const* d_in, const int* in_sizes, int n_in,
                              void* d_out, int out_size, void* d_ws, size_t ws_size,
                              hipStream_t stream) {
  const float* x       = (const float*)d_in[0];
  const float* mu_pop  = (const float*)d_in[1];
  const float* L_pop   = (const float*)d_in[2];
  const float* mu_subj = (const float*)d_in[3];
  const float* L_subj  = (const float*)d_in[4];
  const float* gamma   = (const float*)d_in[5];
  const int*   sid     = (const int*)d_in[6];
  const int*   nsub    = (const int*)d_in[7];

  const int B = in_sizes[6];             // 64
  const int K = in_sizes[1] / DD;        // 12
  const int T = in_sizes[0] / (B * DD);  // 512
  const int P = in_sizes[3] / (K * DD);  // 100

  float* part = (float*)d_ws;  // 1024 floats

  main_kernel<<<B * K + P, BS, 0, stream>>>(x, mu_pop, L_pop, mu_subj, L_subj,
                                            gamma, sid, part, B, T, K, P);
  finalize_kernel<<<1, 256, 0, stream>>>(part, sid, nsub, (float*)d_out, B, K, P,
                                         (float)(B * T));
}